// Round 2
// baseline (498.283 us; speedup 1.0000x reference)
//
#include <hip/hip_runtime.h>
#include <hip/hip_bf16.h>

typedef short short8 __attribute__((ext_vector_type(8)));
typedef float floatx4 __attribute__((ext_vector_type(4)));

#define SCALE_F 0.10206207261596575f

static __device__ __forceinline__ float b2f(unsigned short u){
  unsigned int v = ((unsigned int)u) << 16; float f;
  __builtin_memcpy(&f, &v, 4); return f;
}
static __device__ __forceinline__ unsigned short f2b(float f){
  __hip_bfloat16 h = __float2bfloat16(f);
  unsigned short u; __builtin_memcpy(&u, &h, 2); return u;
}

struct ConvDesc {
  const void* src[17];
  long long off[17];
  int count[17];
};

// ---------------- K0: dtype detect + convert all float tensors to bf16 ----------------
__global__ __launch_bounds__(256) void k_convert(ConvDesc d, unsigned short* dst_base,
                                                 int* flagp, const unsigned int* xprobe)
{
  __shared__ int sflag;
  if (threadIdx.x == 0){
    int pl = 0;
    for (int i = 0; i < 256; ++i){
      unsigned int w = xprobe[1024 + i];
      int e = (w >> 7) & 0xFF;      // exponent field of the LOW ushort viewed as bf16
      if (e >= 90 && e <= 140) pl++;
    }
    // bf16 array: low ushort is a real bf16 of N(0,1) -> ~256 plausible.
    // fp32 array: low ushort is mantissa bits -> ~20% plausible.
    sflag = (pl < 160) ? 1 : 0;      // 1 = inputs are fp32
    if (blockIdx.x == 0 && blockIdx.y == 0) *flagp = sflag;
  }
  __syncthreads();
  const int flag = sflag;
  const int t = blockIdx.y;
  const int cnt = d.count[t];
  unsigned short* dst = dst_base + d.off[t];
  const float* sf = (const float*)d.src[t];
  const unsigned short* su = (const unsigned short*)d.src[t];
  for (int i = blockIdx.x*blockDim.x + threadIdx.x; i < cnt; i += gridDim.x*blockDim.x){
    dst[i] = flag ? f2b(sf[i]) : su[i];
  }
}

// ---------------- K1: QKV GEMM ----------------
__global__ __launch_bounds__(256) void k_qkv(
    const unsigned short* __restrict__ x, const unsigned short* __restrict__ w,
    const unsigned short* __restrict__ bias,
    unsigned short* __restrict__ qr, unsigned short* __restrict__ kr, unsigned short* __restrict__ vr)
{
  const int lane = threadIdx.x & 63;
  const int wv = threadIdx.x >> 6;
  const int col = blockIdx.y*64 + wv*16 + (lane & 15);
  const int kq = (lane >> 4) * 8;
  const unsigned short* wrow = w + col*96 + kq;
  short8 b0 = *(const short8*)(wrow);
  short8 b1 = *(const short8*)(wrow + 32);
  short8 b2 = *(const short8*)(wrow + 64);
  float bv = b2f(bias[col]);
  int which = col / 192; int rem = col - which*192; int head = rem / 96; int d = rem - head*96;
  unsigned short* ob = (which == 0) ? qr : ((which == 1) ? kr : vr);
  const int m_base = blockIdx.x * 64;
  for (int i = 0; i < 4; ++i){
    int mt = m_base + i*16;
    int ma = mt + (lane & 15); if (ma > 100355) ma = 100355;
    const unsigned short* xrow = x + (size_t)ma*96 + kq;
    short8 a0 = *(const short8*)(xrow);
    short8 a1 = *(const short8*)(xrow + 32);
    short8 a2 = *(const short8*)(xrow + 64);
    floatx4 acc = {0.f,0.f,0.f,0.f};
    acc = __builtin_amdgcn_mfma_f32_16x16x32_bf16(a0, b0, acc, 0,0,0);
    acc = __builtin_amdgcn_mfma_f32_16x16x32_bf16(a1, b1, acc, 0,0,0);
    acc = __builtin_amdgcn_mfma_f32_16x16x32_bf16(a2, b2, acc, 0,0,0);
    #pragma unroll
    for (int r = 0; r < 4; ++r){
      int m = mt + (lane >> 4)*4 + r;
      if (m < 100356){
        int bb = m / 25089; int n = m - bb*25089;
        ob[((size_t)(bb*2 + head)*25089 + n)*96 + d] = f2b(acc[r] + bv);
      }
    }
  }
}

// ---------------- K2: q pooling (stride 1,2,2) + LN ----------------
__global__ __launch_bounds__(128) void k_poolq(
    const unsigned short* __restrict__ qr, const unsigned short* __restrict__ cw,
    const unsigned short* __restrict__ g, const unsigned short* __restrict__ bta,
    unsigned short* __restrict__ qp)
{
  const int bid = blockIdx.x;                 // bh*6273 + tok
  const int bh = bid / 6273; const int tok = bid - bh*6273;
  const int d = threadIdx.x;
  const unsigned short* base = qr + (size_t)bh*25089*96;
  float val = 0.f;
  if (d < 96){
    if (tok == 0) val = b2f(base[d]);
    else {
      int s = tok - 1; int t = s / 784; int r2 = s - t*784; int y = r2 / 28; int xx = r2 - y*28;
      const unsigned short* wr = cw + d*27;
      float sum = 0.f;
      for (int dt = 0; dt < 3; ++dt){
        int tt = t + dt - 1; if (tt < 0 || tt >= 8) continue;
        for (int dy = 0; dy < 3; ++dy){
          int yy = 2*y + dy - 1; if (yy < 0 || yy >= 56) continue;
          for (int dx = 0; dx < 3; ++dx){
            int xv = 2*xx + dx - 1; if (xv < 0 || xv >= 56) continue;
            sum += b2f(base[(size_t)(1 + (tt*56 + yy)*56 + xv)*96 + d]) * b2f(wr[(dt*3+dy)*3+dx]);
          }
        }
      }
      val = sum;
    }
  }
  __shared__ float r1[128], r2s[128];
  r1[threadIdx.x] = (d < 96) ? val : 0.f;
  r2s[threadIdx.x] = (d < 96) ? val*val : 0.f;
  __syncthreads();
  for (int off = 64; off > 0; off >>= 1){
    if ((int)threadIdx.x < off){ r1[threadIdx.x] += r1[threadIdx.x+off]; r2s[threadIdx.x] += r2s[threadIdx.x+off]; }
    __syncthreads();
  }
  if (d < 96){
    float mean = r1[0] * (1.f/96.f);
    float var  = r2s[0] * (1.f/96.f) - mean*mean;
    float inv = rsqrtf(var + 1e-5f);
    qp[(size_t)bid*96 + d] = f2b((val - mean)*inv*b2f(g[d]) + b2f(bta[d]));
  }
}

// ---------------- K3: k/v pooling (stride 1,8,8) + LN; v stored transposed ----------------
__global__ __launch_bounds__(128) void k_poolkv(
    const unsigned short* __restrict__ kr, const unsigned short* __restrict__ vr,
    const unsigned short* __restrict__ cwk, const unsigned short* __restrict__ gk, const unsigned short* __restrict__ bk,
    const unsigned short* __restrict__ cwv, const unsigned short* __restrict__ gv, const unsigned short* __restrict__ bv,
    unsigned short* __restrict__ kp, unsigned short* __restrict__ vt)
{
  const int bid = blockIdx.x;            // bh*416 + key
  const int isv = blockIdx.y;
  const int bh = bid / 416; const int key = bid - bh*416;
  const int d = threadIdx.x;
  if (key >= 393){                        // zero pads (keys 393..415)
    if (d < 96){
      if (isv == 0) kp[((size_t)bh*416 + key)*96 + d] = 0;
      else          vt[((size_t)bh*96 + d)*416 + key] = 0;
    }
    return;
  }
  const unsigned short* raw = (isv == 0 ? kr : vr) + (size_t)bh*25089*96;
  const unsigned short* cw = (isv == 0) ? cwk : cwv;
  const unsigned short* g  = (isv == 0) ? gk : gv;
  const unsigned short* bt = (isv == 0) ? bk : bv;
  float val = 0.f;
  if (d < 96){
    if (key == 0) val = b2f(raw[d]);
    else {
      int s = key - 1; int t = s / 49; int r2 = s - t*49; int y = r2 / 7; int xx = r2 - y*7;
      const unsigned short* wr = cw + d*27;
      float sum = 0.f;
      for (int dt = 0; dt < 3; ++dt){
        int tt = t + dt - 1; if (tt < 0 || tt >= 8) continue;
        for (int dy = 0; dy < 3; ++dy){
          int yy = 8*y + dy - 1; if (yy < 0 || yy >= 56) continue;
          for (int dx = 0; dx < 3; ++dx){
            int xv = 8*xx + dx - 1; if (xv < 0 || xv >= 56) continue;
            sum += b2f(raw[(size_t)(1 + (tt*56 + yy)*56 + xv)*96 + d]) * b2f(wr[(dt*3+dy)*3+dx]);
          }
        }
      }
      val = sum;
    }
  }
  __shared__ float r1[128], r2s[128];
  r1[threadIdx.x] = (d < 96) ? val : 0.f;
  r2s[threadIdx.x] = (d < 96) ? val*val : 0.f;
  __syncthreads();
  for (int off = 64; off > 0; off >>= 1){
    if ((int)threadIdx.x < off){ r1[threadIdx.x] += r1[threadIdx.x+off]; r2s[threadIdx.x] += r2s[threadIdx.x+off]; }
    __syncthreads();
  }
  if (d < 96){
    float mean = r1[0] * (1.f/96.f);
    float var  = r2s[0] * (1.f/96.f) - mean*mean;
    float inv = rsqrtf(var + 1e-5f);
    float o = (val - mean)*inv*b2f(g[d]) + b2f(bt[d]);
    if (isv == 0) kp[((size_t)bh*416 + key)*96 + d] = f2b(o);
    else          vt[((size_t)bh*96 + d)*416 + key] = f2b(o);
  }
}

// ---------------- K4: fused attention (16 queries per block) ----------------
#define SSTR 433
#define PSTR 456
#define QSTR 104
__global__ __launch_bounds__(384) void k_attn(
    const unsigned short* __restrict__ qp, const unsigned short* __restrict__ kp,
    const unsigned short* __restrict__ vt,
    const unsigned short* __restrict__ rph, const unsigned short* __restrict__ rpw,
    const unsigned short* __restrict__ rpt,
    unsigned short* __restrict__ ao)
{
  __shared__ __align__(16) unsigned short qs[16*QSTR];
  __shared__ float S[16*SSTR];
  __shared__ __align__(16) unsigned short P[16*PSTR];
  __shared__ float dh[16][7], dw[16][7], dtb[16][8];

  const int qb = blockIdx.x;
  const int bh = blockIdx.y;
  const int bb = bh >> 1, head = bh & 1;
  const int q0 = qb * 16;
  const int tid = threadIdx.x;
  const int lane = tid & 63;
  const int wv = tid >> 6;

  const unsigned short* qbase = qp + (size_t)bh*6273*96;
  const unsigned short* kbase = kp + (size_t)bh*416*96;
  const unsigned short* vbase = vt + (size_t)bh*96*416;

  for (int idx = tid; idx < 16*96; idx += 384){
    int m = idx / 96, c = idx - m*96;
    int gq = q0 + m; if (gq > 6272) gq = 6272;
    qs[m*QSTR + c] = qbase[(size_t)gq*96 + c];
  }
  __syncthreads();

  // per-query rel-pos dot tables: dh[m][ky], dw[m][kx], dtb[m][kt]
  for (int idx = tid; idx < 352; idx += 384){
    int m = idx / 22, e = idx - m*22;
    int gq = q0 + m;
    float dot = 0.f;
    if (gq >= 1 && gq <= 6272){
      int s = gq - 1; int t = s / 784; int r2 = s - t*784; int y = r2 / 28; int xx = r2 - y*28;
      const unsigned short* rrow;
      if (e < 7)       rrow = rph + (size_t)(y  - 4*e       + 24)*96;
      else if (e < 14) rrow = rpw + (size_t)(xx - 4*(e-7)   + 24)*96;
      else             rrow = rpt + (size_t)(t  -   (e-14)  + 7 )*96;
      for (int c = 0; c < 96; c += 8){
        short8 a = *(const short8*)(qs + m*QSTR + c);
        short8 r = *(const short8*)(rrow + c);
        #pragma unroll
        for (int j = 0; j < 8; ++j) dot += b2f((unsigned short)a[j]) * b2f((unsigned short)r[j]);
      }
    }
    if (e < 7) dh[m][e] = dot; else if (e < 14) dw[m][e-7] = dot; else dtb[m][e-14] = dot;
  }
  __syncthreads();

  // QK^T, scale, +rel -> S
  const int kq = (lane >> 4) * 8;
  short8 a0, a1, a2;
  {
    const unsigned short* qrow = qs + (lane & 15)*QSTR + kq;
    a0 = *(const short8*)(qrow);
    a1 = *(const short8*)(qrow + 32);
    a2 = *(const short8*)(qrow + 64);
  }
  for (int t16 = wv; t16 < 26; t16 += 6){
    int key = t16*16 + (lane & 15);
    const unsigned short* krow = kbase + (size_t)key*96 + kq;
    short8 kb0 = *(const short8*)(krow);
    short8 kb1 = *(const short8*)(krow + 32);
    short8 kb2 = *(const short8*)(krow + 64);
    floatx4 acc = {0.f,0.f,0.f,0.f};
    acc = __builtin_amdgcn_mfma_f32_16x16x32_bf16(a0, kb0, acc, 0,0,0);
    acc = __builtin_amdgcn_mfma_f32_16x16x32_bf16(a1, kb1, acc, 0,0,0);
    acc = __builtin_amdgcn_mfma_f32_16x16x32_bf16(a2, kb2, acc, 0,0,0);
    int kt2 = 0, ky = 0, kx = 0;
    if (key >= 1 && key < 393){
      int ks = key - 1; kt2 = ks / 49; int krm = ks - kt2*49; ky = krm / 7; kx = krm - ky*7;
    }
    #pragma unroll
    for (int r = 0; r < 4; ++r){
      int m = (lane >> 4)*4 + r;
      float sv;
      if (key >= 393) sv = -1e30f;
      else {
        sv = acc[r] * SCALE_F;
        if (key >= 1 && (q0 + m) >= 1) sv += dtb[m][kt2] + dh[m][ky] + dw[m][kx];
      }
      S[m*SSTR + key] = sv;
    }
  }
  __syncthreads();

  // row softmax over 416 (pads are -1e30 -> exp 0)
  if (tid < 256){
    int m = tid >> 4, sub = tid & 15;
    float mx = -1e30f;
    for (int j = sub; j < 416; j += 16) mx = fmaxf(mx, S[m*SSTR + j]);
    #pragma unroll
    for (int o = 1; o < 16; o <<= 1) mx = fmaxf(mx, __shfl_xor(mx, o, 64));
    float sum = 0.f;
    for (int j = sub; j < 416; j += 16){
      float e = __expf(S[m*SSTR + j] - mx);
      S[m*SSTR + j] = e; sum += e;
    }
    #pragma unroll
    for (int o = 1; o < 16; o <<= 1) sum += __shfl_xor(sum, o, 64);
    float inv = 1.f / sum;
    for (int j = sub; j < 416; j += 16) P[m*PSTR + j] = f2b(S[m*SSTR + j] * inv);
  }
  __syncthreads();

  // PV + q residual; wave -> d-tile [wv*16, wv*16+16)
  {
    const int dd = wv*16 + (lane & 15);
    const unsigned short* vrow = vbase + (size_t)dd*416 + kq;
    const unsigned short* prow = P + (lane & 15)*PSTR + kq;
    floatx4 acc = {0.f,0.f,0.f,0.f};
    for (int s = 0; s < 13; ++s){
      short8 pa = *(const short8*)(prow + 32*s);
      short8 vb = *(const short8*)(vrow + 32*s);
      acc = __builtin_amdgcn_mfma_f32_16x16x32_bf16(pa, vb, acc, 0,0,0);
    }
    #pragma unroll
    for (int r = 0; r < 4; ++r){
      int m = (lane >> 4)*4 + r;
      int gq = q0 + m;
      if (gq <= 6272){
        float o = acc[r] + b2f(qbase[(size_t)gq*96 + dd]);
        ao[((size_t)bb*6273 + gq)*192 + head*96 + dd] = f2b(o);
      }
    }
  }
}

// ---------------- K5: proj GEMM (flag-aware output dtype) ----------------
__global__ __launch_bounds__(256) void k_proj(
    const unsigned short* __restrict__ ao, const unsigned short* __restrict__ w,
    const unsigned short* __restrict__ bias, void* __restrict__ out, const int* __restrict__ flagp)
{
  const int flag = *flagp;
  const int lane = threadIdx.x & 63;
  const int wv = threadIdx.x >> 6;
  const int c = blockIdx.y*64 + wv*16 + (lane & 15);
  const int kq = (lane >> 4) * 8;
  short8 bfr[6];
  const unsigned short* wrow = w + c*192 + kq;
  #pragma unroll
  for (int s = 0; s < 6; ++s) bfr[s] = *(const short8*)(wrow + 32*s);
  float bv = b2f(bias[c]);
  const int m_base = blockIdx.x * 64;
  for (int i = 0; i < 4; ++i){
    int mt = m_base + i*16;
    int ma = mt + (lane & 15); if (ma > 25091) ma = 25091;
    const unsigned short* arow = ao + (size_t)ma*192 + kq;
    floatx4 acc = {0.f,0.f,0.f,0.f};
    #pragma unroll
    for (int s = 0; s < 6; ++s){
      short8 a = *(const short8*)(arow + 32*s);
      acc = __builtin_amdgcn_mfma_f32_16x16x32_bf16(a, bfr[s], acc, 0,0,0);
    }
    #pragma unroll
    for (int r = 0; r < 4; ++r){
      int m = mt + (lane >> 4)*4 + r;
      if (m < 25092){
        float o = acc[r] + bv;
        if (flag) ((float*)out)[(size_t)m*192 + c] = o;
        else      ((unsigned short*)out)[(size_t)m*192 + c] = f2b(o);
      }
    }
  }
}

extern "C" void kernel_launch(void* const* d_in, const int* in_sizes, int n_in,
                              void* d_out, int out_size, void* d_ws, size_t ws_size,
                              hipStream_t stream)
{
  char* p = (char*)d_ws;
  int* flagp = (int*)p; p += 16;
  unsigned short* conv = (unsigned short*)p;

  // cumulative offsets for the 17 float tensors (order = setup_inputs order)
  ConvDesc desc;
  long long cum = 0;
  for (int i = 0; i < 17; ++i){
    desc.src[i] = d_in[i];
    desc.off[i] = cum;
    desc.count[i] = in_sizes[i];
    cum += in_sizes[i];
  }
  p += (size_t)cum * 2;

  unsigned short* q_raw  = (unsigned short*)p; p += (size_t)19268352*2;
  unsigned short* k_raw  = (unsigned short*)p; p += (size_t)19268352*2;
  unsigned short* v_raw  = (unsigned short*)p; p += (size_t)19268352*2;
  unsigned short* q_pool = (unsigned short*)p; p += (size_t)4817664*2;
  unsigned short* k_pool = (unsigned short*)p; p += (size_t)319488*2;
  unsigned short* v_t    = (unsigned short*)p; p += (size_t)319488*2;
  unsigned short* a_out  = q_raw;   // q_raw is dead after k_poolq; alias to save ws

  const unsigned short* cx     = conv + desc.off[0];
  const unsigned short* cqkv_w = conv + desc.off[1];
  const unsigned short* cqkv_b = conv + desc.off[2];
  const unsigned short* cproj_w= conv + desc.off[3];
  const unsigned short* cproj_b= conv + desc.off[4];
  const unsigned short* cpq_w  = conv + desc.off[5];
  const unsigned short* cnq_g  = conv + desc.off[6];
  const unsigned short* cnq_b  = conv + desc.off[7];
  const unsigned short* cpk_w  = conv + desc.off[8];
  const unsigned short* cnk_g  = conv + desc.off[9];
  const unsigned short* cnk_b  = conv + desc.off[10];
  const unsigned short* cpv_w  = conv + desc.off[11];
  const unsigned short* cnv_g  = conv + desc.off[12];
  const unsigned short* cnv_b  = conv + desc.off[13];
  const unsigned short* crph   = conv + desc.off[14];
  const unsigned short* crpw   = conv + desc.off[15];
  const unsigned short* crpt   = conv + desc.off[16];

  k_convert<<<dim3(592, 17), 256, 0, stream>>>(desc, conv, flagp, (const unsigned int*)d_in[0]);
  k_qkv  <<<dim3(1569, 9), 256, 0, stream>>>(cx, cqkv_w, cqkv_b, q_raw, k_raw, v_raw);
  k_poolq<<<dim3(8*6273), 128, 0, stream>>>(q_raw, cpq_w, cnq_g, cnq_b, q_pool);
  k_poolkv<<<dim3(8*416, 2), 128, 0, stream>>>(k_raw, v_raw, cpk_w, cnk_g, cnk_b, cpv_w, cnv_g, cnv_b, k_pool, v_t);
  k_attn <<<dim3(393, 8), 384, 0, stream>>>(q_pool, k_pool, v_t, crph, crpw, crpt, a_out);
  k_proj <<<dim3(393, 3), 256, 0, stream>>>(a_out, cproj_w, cproj_b, d_out, flagp);
}

// Round 3
// 365.563 us; speedup vs baseline: 1.3631x; 1.3631x over previous
//
#include <hip/hip_runtime.h>
#include <hip/hip_bf16.h>

typedef short short8 __attribute__((ext_vector_type(8)));
typedef float floatx4 __attribute__((ext_vector_type(4)));

#define SCALE_F 0.10206207261596575f

static __device__ __forceinline__ float b2f(unsigned short u){
  unsigned int v = ((unsigned int)u) << 16; float f;
  __builtin_memcpy(&f, &v, 4); return f;
}
static __device__ __forceinline__ unsigned short f2b(float f){
  __hip_bfloat16 h = __float2bfloat16(f);
  unsigned short u; __builtin_memcpy(&u, &h, 2); return u;
}

struct ConvDesc {
  const void* src[17];
  long long off[17];
  int count[17];
};

// ---------------- K0: dtype detect + convert all float tensors to bf16 ----------------
__global__ __launch_bounds__(256) void k_convert(ConvDesc d, unsigned short* dst_base,
                                                 int* flagp, const unsigned int* xprobe)
{
  __shared__ int sflag;
  if (threadIdx.x < 64){
    unsigned int w = xprobe[1024 + threadIdx.x];
    int e = (w >> 7) & 0xFF;           // exponent of LOW ushort viewed as bf16
    int pl = (e >= 90 && e <= 140) ? 1 : 0;
    unsigned long long m = __ballot(pl);
    if (threadIdx.x == 0){
      sflag = (__popcll(m) < 40) ? 1 : 0;   // 1 = inputs are fp32
      if (blockIdx.x == 0 && blockIdx.y == 0) *flagp = sflag;
    }
  }
  __syncthreads();
  const int flag = sflag;
  const int t = blockIdx.y;
  const int cnt = d.count[t];
  unsigned short* dst = dst_base + d.off[t];
  const float* sf = (const float*)d.src[t];
  const unsigned short* su = (const unsigned short*)d.src[t];
  for (int i = blockIdx.x*blockDim.x + threadIdx.x; i < cnt; i += gridDim.x*blockDim.x){
    dst[i] = flag ? f2b(sf[i]) : su[i];
  }
}

// ---------------- K1: QKV GEMM (x read once per row-tile; all 576 cols per block) ------
__global__ __launch_bounds__(256) void k_qkv(
    const unsigned short* __restrict__ x, const unsigned short* __restrict__ w,
    const unsigned short* __restrict__ bias,
    unsigned short* __restrict__ qr, unsigned short* __restrict__ kr, unsigned short* __restrict__ vr)
{
  const int lane = threadIdx.x & 63;
  const int wv = threadIdx.x >> 6;
  const int kq = (lane >> 4) * 8;
  const int m_base = blockIdx.x * 64 + wv * 16;   // this wave's 16 rows

  int ma = m_base + (lane & 15); if (ma > 100355) ma = 100355;
  const unsigned short* xrow = x + (size_t)ma*96 + kq;
  short8 a0 = *(const short8*)(xrow);
  short8 a1 = *(const short8*)(xrow + 32);
  short8 a2 = *(const short8*)(xrow + 64);

  // per-lane row bases (head-0 offset); head adds 2*25089*96/2 elements
  size_t base0[4];
  int mrow[4];
  #pragma unroll
  for (int r = 0; r < 4; ++r){
    int m = m_base + (lane >> 4)*4 + r;
    mrow[r] = m;
    int bb = m / 25089; int n = m - bb*25089;
    base0[r] = ((size_t)(bb*2)*25089 + n)*96;
  }

  for (int ct = 0; ct < 36; ++ct){
    int col = ct*16 + (lane & 15);
    const unsigned short* wrow = w + col*96 + kq;
    short8 b0 = *(const short8*)(wrow);
    short8 b1 = *(const short8*)(wrow + 32);
    short8 b2 = *(const short8*)(wrow + 64);
    float bv = b2f(bias[col]);
    floatx4 acc = {0.f,0.f,0.f,0.f};
    acc = __builtin_amdgcn_mfma_f32_16x16x32_bf16(a0, b0, acc, 0,0,0);
    acc = __builtin_amdgcn_mfma_f32_16x16x32_bf16(a1, b1, acc, 0,0,0);
    acc = __builtin_amdgcn_mfma_f32_16x16x32_bf16(a2, b2, acc, 0,0,0);
    int which = col / 192; int rem = col - which*192; int head = rem / 96; int d = rem - head*96;
    unsigned short* ob = (which == 0) ? qr : ((which == 1) ? kr : vr);
    size_t hoff = (size_t)head * 2408544 + d;
    #pragma unroll
    for (int r = 0; r < 4; ++r){
      if (mrow[r] < 100356) ob[base0[r] + hoff] = f2b(acc[r] + bv);
    }
  }
}

// ---------------- K2: q pooling (stride 1,2,2) + LN — tile-based, vectorized ----------
// block = (y in [0,28), t in [0,8), bh in [0,8)); threads 384: tid=x*12+dg for x<28.
// block (y==0,t==0) additionally handles the cls token with threads 348..359.
__global__ __launch_bounds__(384) void k_poolq(
    const unsigned short* __restrict__ qr, const unsigned short* __restrict__ cw,
    const unsigned short* __restrict__ g, const unsigned short* __restrict__ bta,
    unsigned short* __restrict__ qp)
{
  __shared__ float wlds[27*96];
  __shared__ float gls[96], bls[96];
  __shared__ float ls1[29*12], ls2[29*12];
  __shared__ float lmean[29], linv[29];

  const int y  = blockIdx.x;
  const int t  = blockIdx.y;
  const int bh = blockIdx.z;
  const int tid = threadIdx.x;
  const bool has_cls = (y == 0 && t == 0);
  const unsigned short* base = qr + (size_t)bh*2408544;

  for (int idx = tid; idx < 27*96; idx += 384){
    int tap = idx / 96, d = idx - tap*96;
    wlds[idx] = b2f(cw[d*27 + tap]);
  }
  for (int idx = tid; idx < 96; idx += 384){
    gls[idx] = b2f(g[idx]); bls[idx] = b2f(bta[idx]);
  }
  __syncthreads();

  const int x = tid / 12, dg = tid - x*12;
  float val[8] = {0,0,0,0,0,0,0,0};

  if (x < 28){
    #pragma unroll
    for (int dt = 0; dt < 3; ++dt){
      int tt = t + dt - 1; if (tt < 0 || tt >= 8) continue;
      #pragma unroll
      for (int dy = 0; dy < 3; ++dy){
        int yy = 2*y + dy - 1; if (yy < 0 || yy >= 56) continue;
        #pragma unroll
        for (int dx = 0; dx < 3; ++dx){
          int xv = 2*x + dx - 1; if (xv < 0 || xv >= 56) continue;
          const int tap = (dt*3+dy)*3+dx;
          short8 v = *(const short8*)(base + (size_t)(1 + (tt*56 + yy)*56 + xv)*96 + dg*8);
          const float* wr = wlds + tap*96 + dg*8;
          #pragma unroll
          for (int j = 0; j < 8; ++j) val[j] += b2f((unsigned short)v[j]) * wr[j];
        }
      }
    }
    float s1 = 0.f, s2 = 0.f;
    #pragma unroll
    for (int j = 0; j < 8; ++j){ s1 += val[j]; s2 += val[j]*val[j]; }
    ls1[x*12+dg] = s1; ls2[x*12+dg] = s2;
  } else if (has_cls && tid >= 348 && tid < 360){
    int cdg = tid - 348;
    short8 v = *(const short8*)(base + cdg*8);
    float s1 = 0.f, s2 = 0.f;
    #pragma unroll
    for (int j = 0; j < 8; ++j){ val[j] = b2f((unsigned short)v[j]); s1 += val[j]; s2 += val[j]*val[j]; }
    ls1[28*12+cdg] = s1; ls2[28*12+cdg] = s2;
  }
  __syncthreads();

  if (tid < 28 || (tid == 28 && has_cls)){
    float s1 = 0.f, s2 = 0.f;
    #pragma unroll
    for (int k = 0; k < 12; ++k){ s1 += ls1[tid*12+k]; s2 += ls2[tid*12+k]; }
    float mean = s1 * (1.f/96.f);
    float var  = s2 * (1.f/96.f) - mean*mean;
    lmean[tid] = mean; linv[tid] = rsqrtf(var + 1e-5f);
  }
  __syncthreads();

  if (x < 28){
    float mean = lmean[x], inv = linv[x];
    int tok = 1 + (t*28 + y)*28 + x;
    short8 o;
    #pragma unroll
    for (int j = 0; j < 8; ++j)
      o[j] = (short)f2b((val[j] - mean)*inv*gls[dg*8+j] + bls[dg*8+j]);
    *(short8*)(qp + ((size_t)bh*6273 + tok)*96 + dg*8) = o;
  } else if (has_cls && tid >= 348 && tid < 360){
    int cdg = tid - 348;
    float mean = lmean[28], inv = linv[28];
    short8 o;
    #pragma unroll
    for (int j = 0; j < 8; ++j)
      o[j] = (short)f2b((val[j] - mean)*inv*gls[cdg*8+j] + bls[cdg*8+j]);
    *(short8*)(qp + (size_t)bh*6273*96 + cdg*8) = o;
  }
}

// ---------------- K3: k/v pooling (stride 1,8,8) + LN; v stored transposed ----------------
__global__ __launch_bounds__(128) void k_poolkv(
    const unsigned short* __restrict__ kr, const unsigned short* __restrict__ vr,
    const unsigned short* __restrict__ cwk, const unsigned short* __restrict__ gk, const unsigned short* __restrict__ bk,
    const unsigned short* __restrict__ cwv, const unsigned short* __restrict__ gv, const unsigned short* __restrict__ bv,
    unsigned short* __restrict__ kp, unsigned short* __restrict__ vt)
{
  const int bid = blockIdx.x;            // bh*416 + key
  const int isv = blockIdx.y;
  const int bh = bid / 416; const int key = bid - bh*416;
  const int d = threadIdx.x;
  if (key >= 393){                        // zero pads (keys 393..415)
    if (d < 96){
      if (isv == 0) kp[((size_t)bh*416 + key)*96 + d] = 0;
      else          vt[((size_t)bh*96 + d)*416 + key] = 0;
    }
    return;
  }
  const unsigned short* raw = (isv == 0 ? kr : vr) + (size_t)bh*2408544;
  const unsigned short* cw = (isv == 0) ? cwk : cwv;
  const unsigned short* g  = (isv == 0) ? gk : gv;
  const unsigned short* bt = (isv == 0) ? bk : bv;
  float val = 0.f;
  if (d < 96){
    if (key == 0) val = b2f(raw[d]);
    else {
      int s = key - 1; int t = s / 49; int r2 = s - t*49; int y = r2 / 7; int xx = r2 - y*7;
      const unsigned short* wr = cw + d*27;
      float sum = 0.f;
      for (int dt = 0; dt < 3; ++dt){
        int tt = t + dt - 1; if (tt < 0 || tt >= 8) continue;
        for (int dy = 0; dy < 3; ++dy){
          int yy = 8*y + dy - 1; if (yy < 0 || yy >= 56) continue;
          for (int dx = 0; dx < 3; ++dx){
            int xv = 8*xx + dx - 1; if (xv < 0 || xv >= 56) continue;
            sum += b2f(raw[(size_t)(1 + (tt*56 + yy)*56 + xv)*96 + d]) * b2f(wr[(dt*3+dy)*3+dx]);
          }
        }
      }
      val = sum;
    }
  }
  __shared__ float r1[128], r2s[128];
  r1[threadIdx.x] = (d < 96) ? val : 0.f;
  r2s[threadIdx.x] = (d < 96) ? val*val : 0.f;
  __syncthreads();
  for (int off = 64; off > 0; off >>= 1){
    if ((int)threadIdx.x < off){ r1[threadIdx.x] += r1[threadIdx.x+off]; r2s[threadIdx.x] += r2s[threadIdx.x+off]; }
    __syncthreads();
  }
  if (d < 96){
    float mean = r1[0] * (1.f/96.f);
    float var  = r2s[0] * (1.f/96.f) - mean*mean;
    float inv = rsqrtf(var + 1e-5f);
    float o = (val - mean)*inv*b2f(g[d]) + b2f(bt[d]);
    if (isv == 0) kp[((size_t)bh*416 + key)*96 + d] = f2b(o);
    else          vt[((size_t)bh*96 + d)*416 + key] = f2b(o);
  }
}

// ---------------- K4: fused attention (16 queries per block) ----------------
#define SSTR 433
#define PSTR 456
#define QSTR 104
__global__ __launch_bounds__(384) void k_attn(
    const unsigned short* __restrict__ qp, const unsigned short* __restrict__ kp,
    const unsigned short* __restrict__ vt,
    const unsigned short* __restrict__ rph, const unsigned short* __restrict__ rpw,
    const unsigned short* __restrict__ rpt,
    unsigned short* __restrict__ ao)
{
  __shared__ __align__(16) unsigned short qs[16*QSTR];
  __shared__ float S[16*SSTR];
  __shared__ __align__(16) unsigned short P[16*PSTR];
  __shared__ float dh[16][7], dw[16][7], dtb[16][8];

  const int qb = blockIdx.x;
  const int bh = blockIdx.y;
  const int bb = bh >> 1, head = bh & 1;
  const int q0 = qb * 16;
  const int tid = threadIdx.x;
  const int lane = tid & 63;
  const int wv = tid >> 6;

  const unsigned short* qbase = qp + (size_t)bh*6273*96;
  const unsigned short* kbase = kp + (size_t)bh*416*96;
  const unsigned short* vbase = vt + (size_t)bh*96*416;

  for (int idx = tid; idx < 16*96; idx += 384){
    int m = idx / 96, c = idx - m*96;
    int gq = q0 + m; if (gq > 6272) gq = 6272;
    qs[m*QSTR + c] = qbase[(size_t)gq*96 + c];
  }
  __syncthreads();

  for (int idx = tid; idx < 352; idx += 384){
    int m = idx / 22, e = idx - m*22;
    int gq = q0 + m;
    float dot = 0.f;
    if (gq >= 1 && gq <= 6272){
      int s = gq - 1; int t = s / 784; int r2 = s - t*784; int y = r2 / 28; int xx = r2 - y*28;
      const unsigned short* rrow;
      if (e < 7)       rrow = rph + (size_t)(y  - 4*e       + 24)*96;
      else if (e < 14) rrow = rpw + (size_t)(xx - 4*(e-7)   + 24)*96;
      else             rrow = rpt + (size_t)(t  -   (e-14)  + 7 )*96;
      for (int c = 0; c < 96; c += 8){
        short8 a = *(const short8*)(qs + m*QSTR + c);
        short8 r = *(const short8*)(rrow + c);
        #pragma unroll
        for (int j = 0; j < 8; ++j) dot += b2f((unsigned short)a[j]) * b2f((unsigned short)r[j]);
      }
    }
    if (e < 7) dh[m][e] = dot; else if (e < 14) dw[m][e-7] = dot; else dtb[m][e-14] = dot;
  }
  __syncthreads();

  const int kq = (lane >> 4) * 8;
  short8 a0, a1, a2;
  {
    const unsigned short* qrow = qs + (lane & 15)*QSTR + kq;
    a0 = *(const short8*)(qrow);
    a1 = *(const short8*)(qrow + 32);
    a2 = *(const short8*)(qrow + 64);
  }
  for (int t16 = wv; t16 < 26; t16 += 6){
    int key = t16*16 + (lane & 15);
    const unsigned short* krow = kbase + (size_t)key*96 + kq;
    short8 kb0 = *(const short8*)(krow);
    short8 kb1 = *(const short8*)(krow + 32);
    short8 kb2 = *(const short8*)(krow + 64);
    floatx4 acc = {0.f,0.f,0.f,0.f};
    acc = __builtin_amdgcn_mfma_f32_16x16x32_bf16(a0, kb0, acc, 0,0,0);
    acc = __builtin_amdgcn_mfma_f32_16x16x32_bf16(a1, kb1, acc, 0,0,0);
    acc = __builtin_amdgcn_mfma_f32_16x16x32_bf16(a2, kb2, acc, 0,0,0);
    int kt2 = 0, ky = 0, kx = 0;
    if (key >= 1 && key < 393){
      int ks = key - 1; kt2 = ks / 49; int krm = ks - kt2*49; ky = krm / 7; kx = krm - ky*7;
    }
    #pragma unroll
    for (int r = 0; r < 4; ++r){
      int m = (lane >> 4)*4 + r;
      float sv;
      if (key >= 393) sv = -1e30f;
      else {
        sv = acc[r] * SCALE_F;
        if (key >= 1 && (q0 + m) >= 1) sv += dtb[m][kt2] + dh[m][ky] + dw[m][kx];
      }
      S[m*SSTR + key] = sv;
    }
  }
  __syncthreads();

  if (tid < 256){
    int m = tid >> 4, sub = tid & 15;
    float mx = -1e30f;
    for (int j = sub; j < 416; j += 16) mx = fmaxf(mx, S[m*SSTR + j]);
    #pragma unroll
    for (int o = 1; o < 16; o <<= 1) mx = fmaxf(mx, __shfl_xor(mx, o, 64));
    float sum = 0.f;
    for (int j = sub; j < 416; j += 16){
      float e = __expf(S[m*SSTR + j] - mx);
      S[m*SSTR + j] = e; sum += e;
    }
    #pragma unroll
    for (int o = 1; o < 16; o <<= 1) sum += __shfl_xor(sum, o, 64);
    float inv = 1.f / sum;
    for (int j = sub; j < 416; j += 16) P[m*PSTR + j] = f2b(S[m*SSTR + j] * inv);
  }
  __syncthreads();

  {
    const int dd = wv*16 + (lane & 15);
    const unsigned short* vrow = vbase + (size_t)dd*416 + kq;
    const unsigned short* prow = P + (lane & 15)*PSTR + kq;
    floatx4 acc = {0.f,0.f,0.f,0.f};
    for (int s = 0; s < 13; ++s){
      short8 pa = *(const short8*)(prow + 32*s);
      short8 vb = *(const short8*)(vrow + 32*s);
      acc = __builtin_amdgcn_mfma_f32_16x16x32_bf16(pa, vb, acc, 0,0,0);
    }
    #pragma unroll
    for (int r = 0; r < 4; ++r){
      int m = (lane >> 4)*4 + r;
      int gq = q0 + m;
      if (gq <= 6272){
        float o = acc[r] + b2f(qbase[(size_t)gq*96 + dd]);
        ao[((size_t)bb*6273 + gq)*192 + head*96 + dd] = f2b(o);
      }
    }
  }
}

// ---------------- K5: proj GEMM (flag-aware output dtype) ----------------
__global__ __launch_bounds__(256) void k_proj(
    const unsigned short* __restrict__ ao, const unsigned short* __restrict__ w,
    const unsigned short* __restrict__ bias, void* __restrict__ out, const int* __restrict__ flagp)
{
  const int flag = *flagp;
  const int lane = threadIdx.x & 63;
  const int wv = threadIdx.x >> 6;
  const int c = blockIdx.y*64 + wv*16 + (lane & 15);
  const int kq = (lane >> 4) * 8;
  short8 bfr[6];
  const unsigned short* wrow = w + c*192 + kq;
  #pragma unroll
  for (int s = 0; s < 6; ++s) bfr[s] = *(const short8*)(wrow + 32*s);
  float bv = b2f(bias[c]);
  const int m_base = blockIdx.x * 64;
  for (int i = 0; i < 4; ++i){
    int mt = m_base + i*16;
    int ma = mt + (lane & 15); if (ma > 25091) ma = 25091;
    const unsigned short* arow = ao + (size_t)ma*192 + kq;
    floatx4 acc = {0.f,0.f,0.f,0.f};
    #pragma unroll
    for (int s = 0; s < 6; ++s){
      short8 a = *(const short8*)(arow + 32*s);
      acc = __builtin_amdgcn_mfma_f32_16x16x32_bf16(a, bfr[s], acc, 0,0,0);
    }
    #pragma unroll
    for (int r = 0; r < 4; ++r){
      int m = mt + (lane >> 4)*4 + r;
      if (m < 25092){
        float o = acc[r] + bv;
        if (flag) ((float*)out)[(size_t)m*192 + c] = o;
        else      ((unsigned short*)out)[(size_t)m*192 + c] = f2b(o);
      }
    }
  }
}

extern "C" void kernel_launch(void* const* d_in, const int* in_sizes, int n_in,
                              void* d_out, int out_size, void* d_ws, size_t ws_size,
                              hipStream_t stream)
{
  char* p = (char*)d_ws;
  int* flagp = (int*)p; p += 16;
  unsigned short* conv = (unsigned short*)p;

  ConvDesc desc;
  long long cum = 0;
  for (int i = 0; i < 17; ++i){
    desc.src[i] = d_in[i];
    desc.off[i] = cum;
    desc.count[i] = in_sizes[i];
    cum += in_sizes[i];
  }
  p += (size_t)cum * 2;

  unsigned short* q_raw  = (unsigned short*)p; p += (size_t)19268352*2;
  unsigned short* k_raw  = (unsigned short*)p; p += (size_t)19268352*2;
  unsigned short* v_raw  = (unsigned short*)p; p += (size_t)19268352*2;
  unsigned short* q_pool = (unsigned short*)p; p += (size_t)4817664*2;
  unsigned short* k_pool = (unsigned short*)p; p += (size_t)319488*2;
  unsigned short* v_t    = (unsigned short*)p; p += (size_t)319488*2;
  unsigned short* a_out  = q_raw;   // q_raw dead after k_poolq

  const unsigned short* cx     = conv + desc.off[0];
  const unsigned short* cqkv_w = conv + desc.off[1];
  const unsigned short* cqkv_b = conv + desc.off[2];
  const unsigned short* cproj_w= conv + desc.off[3];
  const unsigned short* cproj_b= conv + desc.off[4];
  const unsigned short* cpq_w  = conv + desc.off[5];
  const unsigned short* cnq_g  = conv + desc.off[6];
  const unsigned short* cnq_b  = conv + desc.off[7];
  const unsigned short* cpk_w  = conv + desc.off[8];
  const unsigned short* cnk_g  = conv + desc.off[9];
  const unsigned short* cnk_b  = conv + desc.off[10];
  const unsigned short* cpv_w  = conv + desc.off[11];
  const unsigned short* cnv_g  = conv + desc.off[12];
  const unsigned short* cnv_b  = conv + desc.off[13];
  const unsigned short* crph   = conv + desc.off[14];
  const unsigned short* crpw   = conv + desc.off[15];
  const unsigned short* crpt   = conv + desc.off[16];

  k_convert<<<dim3(592, 17), 256, 0, stream>>>(desc, conv, flagp, (const unsigned int*)d_in[0]);
  k_qkv  <<<dim3(1569), 256, 0, stream>>>(cx, cqkv_w, cqkv_b, q_raw, k_raw, v_raw);
  k_poolq<<<dim3(28, 8, 8), 384, 0, stream>>>(q_raw, cpq_w, cnq_g, cnq_b, q_pool);
  k_poolkv<<<dim3(8*416, 2), 128, 0, stream>>>(k_raw, v_raw, cpk_w, cnk_g, cnk_b, cpv_w, cnv_g, cnv_b, k_pool, v_t);
  k_attn <<<dim3(393, 8), 384, 0, stream>>>(q_pool, k_pool, v_t, crph, crpw, crpt, a_out);
  k_proj <<<dim3(393, 3), 256, 0, stream>>>(a_out, cproj_w, cproj_b, d_out, flagp);
}